// Round 2
// baseline (2227.658 us; speedup 1.0000x reference)
//
#include <hip/hip_runtime.h>

// GAWADecoder on MI355X (gfx950). All tensors fp32 in global; bf16 MFMA inside.
// R4 post-mortem: decoder_loop is weight-traffic-bound: every block re-streams
// the full 1.18MB of loop weights each step (FETCH scaled with block count,
// 4.3GB; MfmaUtil stuck at 4%). R5: WEIGHT-STATIONARY inversion. 256 blocks =
// 16 row-groups x 16 col-groups; each block owns 256 rows x 16 h-cols and
// keeps its 72KB weight slice in LDS for the whole loop. Per step it reads
// only h-activation fragments (~384KB) and writes its 16-col h slices.
// Cross-block ordering via per-row-group flag counters (device-scope atomics
// + __threadfence); co-residency via hipLaunchCooperativeKernel. XCD-clustered
// block mapping keeps each row-group's 16 peers on one XCD's L2.

typedef __bf16 bf16;
typedef __attribute__((ext_vector_type(8))) __bf16 bf16x8;
typedef __attribute__((ext_vector_type(4))) __bf16 bf16x4;
typedef __attribute__((ext_vector_type(4))) float fx4;

#define MFMA16(a, b, c) __builtin_amdgcn_mfma_f32_16x16x32_bf16(a, b, c, 0, 0, 0)

__device__ __forceinline__ float sigm(float x) { return 1.0f / (1.0f + expf(-x)); }

// load 8 consecutive fp32, round to bf16x8 (MFMA operand)
__device__ __forceinline__ bf16x8 cvt8(const float* __restrict__ p) {
    float4 u = ((const float4*)p)[0];
    float4 v = ((const float4*)p)[1];
    bf16x8 r;
    r[0] = (bf16)u.x; r[1] = (bf16)u.y; r[2] = (bf16)u.z; r[3] = (bf16)u.w;
    r[4] = (bf16)v.x; r[5] = (bf16)v.y; r[6] = (bf16)v.z; r[7] = (bf16)v.w;
    return r;
}

// bf16x8 h + fp32[8] -> bf16x8 (logits A-fragment: h1 + attn_out)
__device__ __forceinline__ bf16x8 addcvt8(bf16x8 h, const float* __restrict__ p) {
    float4 u = ((const float4*)p)[0];
    float4 v = ((const float4*)p)[1];
    bf16x8 r;
    r[0] = (bf16)((float)h[0] + u.x); r[1] = (bf16)((float)h[1] + u.y);
    r[2] = (bf16)((float)h[2] + u.z); r[3] = (bf16)((float)h[3] + u.w);
    r[4] = (bf16)((float)h[4] + v.x); r[5] = (bf16)((float)h[5] + v.y);
    r[6] = (bf16)((float)h[6] + v.z); r[7] = (bf16)((float)h[7] + v.w);
    return r;
}

// ---------------------------------------------------------------------------
__global__ void f2b(const float* __restrict__ s, bf16* __restrict__ d, int n) {
    int i = (blockIdx.x * 256 + threadIdx.x) * 4;
    if (i >= n) return;
    float4 v = *(const float4*)(s + i);
    bf16x4 o;
    o[0] = (bf16)v.x; o[1] = (bf16)v.y; o[2] = (bf16)v.z; o[3] = (bf16)v.w;
    *(bf16x4*)(d + i) = o;
}

__global__ void zero_u32(unsigned* __restrict__ p, int n) {
    int i = blockIdx.x * 256 + threadIdx.x;
    if (i < n) p[i] = 0u;
}

// ---------------------------------------------------------------------------
// out[M,N] = act(A[M,K] @ W[N,K]^T + bias), fp32 in global; bf16 MFMA inside.
// ---------------------------------------------------------------------------
__global__ __launch_bounds__(256, 4) void gemm_bt(
    const float* __restrict__ A, int lda,
    const float* __restrict__ W, int ldw,
    const float* __restrict__ bias,
    float* __restrict__ out, int ldo, int act_tanh, int K)
{
    const int tid  = threadIdx.x;
    const int wid  = tid >> 6;
    const int lane = tid & 63;
    const int quad = lane >> 4;
    const int l16  = lane & 15;
    const int m0   = blockIdx.x * 32;
    const int n0   = blockIdx.y * 256 + wid * 64;

    fx4 acc[4][2];
#pragma unroll
    for (int j = 0; j < 4; ++j) {
        acc[j][0] = fx4{0.f, 0.f, 0.f, 0.f};
        acc[j][1] = fx4{0.f, 0.f, 0.f, 0.f};
    }

    const float* a0p = A + (size_t)(m0 + l16) * lda + quad * 8;
    const float* a1p = A + (size_t)(m0 + 16 + l16) * lda + quad * 8;

    for (int k0 = 0; k0 < K; k0 += 32) {
        bf16x8 a0 = cvt8(a0p + k0);
        bf16x8 a1 = cvt8(a1p + k0);
#pragma unroll
        for (int j = 0; j < 4; ++j) {
            bf16x8 b = cvt8(W + (size_t)(n0 + j * 16 + l16) * ldw + k0 + quad * 8);
            acc[j][0] = MFMA16(a0, b, acc[j][0]);
            acc[j][1] = MFMA16(a1, b, acc[j][1]);
        }
    }

#pragma unroll
    for (int j = 0; j < 4; ++j) {
        int n = n0 + j * 16 + l16;
        float bv = bias ? bias[n] : 0.0f;
#pragma unroll
        for (int rt = 0; rt < 2; ++rt)
#pragma unroll
            for (int r = 0; r < 4; ++r) {
                int m = m0 + rt * 16 + quad * 4 + r;
                float v = acc[j][rt][r] + bv;
                if (act_tanh) v = tanhf(v);
                out[(size_t)m * ldo + n] = v;
            }
    }
}

// ---------------------------------------------------------------------------
// Weight-stationary recurrent kernel. Cooperative launch, 256 blocks x 1024.
// Block (rg,cg): rows [rg*256, rg*256+256), h-cols [cg*16, cg*16+16).
// Weights for its cols (3 mats x 3 gates x 16 cols x 256 k, bf16) live in LDS
// (72KB, XOR-swizzled vs the 512B-stride bank conflict). Per step:
//   phase A: gh0 = h0(t)@w_hh0^T and gh1 = h1(t)@w_hh1^T (A-frags from global)
//            -> layer-0 gates -> write h0(t+1) col-slice -> arrive c0[rg].
//   phase B: wait c0[rg] full -> gi1 = h0(t+1)@w_ih1^T -> layer-1 gates
//            -> write h1(t+1) slice + h1all archive -> arrive c1[rg].
// Flags are per-row-group (16 producers each); row-groups drift independently.
// XCD clustering: rg = (bid&7)*2 + (bid>>3 & 1), cg = bid>>4  => all 16 peers
// of a row-group sit on one XCD, so h slices exchange through one L2.
// ---------------------------------------------------------------------------
__global__ __launch_bounds__(1024, 4) void decoder_loop(
    const int*   __restrict__ tgt,      // (4096,32)
    const float* __restrict__ h0i,      // (4096,256)
    const float* __restrict__ gword,    // (4096,768) eword part of gi0 (+b_ih0)
    const float* __restrict__ cproj,    // (256,768)  char_emb @ w_ih0[:,:64]^T
    const bf16*  __restrict__ w_hh0, const float* __restrict__ b_hh0,
    const bf16*  __restrict__ w_ih1, const float* __restrict__ b_ih1,
    const bf16*  __restrict__ w_hh1, const float* __restrict__ b_hh1,
    bf16* __restrict__ h0g,             // [2][4096][256] ping-pong
    bf16* __restrict__ h1g,             // [2][4096][256] ping-pong
    unsigned* __restrict__ c0f,         // [16*32] h0-version counters (128B apart)
    unsigned* __restrict__ c1f,         // [16*32] h1-version counters
    bf16* __restrict__ h1all)           // (4096,32,256) bf16
{
    __shared__ __align__(16) bf16 wlds[3 * 48 * 256];   // 72KB: [mat][gate*16+col][256]

    const int tid  = threadIdx.x;
    const int wv   = tid >> 6;     // 0..15
    const int lane = tid & 63;
    const int quad = lane >> 4;
    const int l16  = lane & 15;
    const int bid  = blockIdx.x;
    const int rg   = (bid & 7) * 2 + ((bid >> 3) & 1);   // row-group, XCD-clustered
    const int cg   = bid >> 4;                            // col-group
    const int R0   = rg * 256 + wv * 16;                  // wave's A-row base
    const int colg = cg * 16 + l16;                       // lane's h/gate column
    const int rowc = rg * 256 + wv * 16 + quad * 4;       // lane's first C row
    const int xw   = (l16 & 7) << 3;                      // LDS XOR swizzle (elems)
    const size_t HSZ = (size_t)4096 * 256;

    // ---- stage weight slices to LDS (once; swizzled) ----
    const bf16* Ws[3] = { w_hh0, w_ih1, w_hh1 };
#pragma unroll
    for (int m = 0; m < 3; ++m)
        for (int v = tid; v < 1536; v += 1024) {
            int lr = v >> 5, k8 = v & 31;          // lr = gate*16+col, k8 = vec8 idx
            int g = lr >> 4, c = lr & 15;
            bf16x8 w = *(const bf16x8*)(Ws[m] + (size_t)(g * 256 + cg * 16 + c) * 256 + k8 * 8);
            *(bf16x8*)&wlds[(m * 48 + lr) * 256 + ((k8 * 8) ^ ((lr & 7) << 3))] = w;
        }

    // ---- step-invariant per-lane state ----
    float h0m[4], h1m[4], gwv[3][4], cpv[3][4];
    float bh0[3], bi1[3], bh1[3];
#pragma unroll
    for (int g = 0; g < 3; ++g) {
        bh0[g] = b_hh0[g * 256 + colg];
        bi1[g] = b_ih1[g * 256 + colg];
        bh1[g] = b_hh1[g * 256 + colg];
    }
#pragma unroll
    for (int r = 0; r < 4; ++r) {
        int row = rowc + r;
        float v = h0i[(size_t)row * 256 + colg];
        h0m[r] = v; h1m[r] = v;
        bf16 bv = (bf16)v;
        h0g[(size_t)row * 256 + colg] = bv;    // version 0 -> buffer 0
        h1g[(size_t)row * 256 + colg] = bv;
#pragma unroll
        for (int g = 0; g < 3; ++g)
            gwv[g][r] = gword[(size_t)row * 768 + g * 256 + colg];
    }
    // t=0 char input is BOS(=1) for every row
#pragma unroll
    for (int g = 0; g < 3; ++g) {
        float v = cproj[768 + g * 256 + colg];
#pragma unroll
        for (int r = 0; r < 4; ++r) cpv[g][r] = v;
    }

    __syncthreads();   // LDS staged; init stores drained to L2
    if (tid == 0) {
        __threadfence();   // flush L2 -> LLC so peers (and counters) see v0
        __hip_atomic_fetch_add(&c0f[rg * 32], 1u, __ATOMIC_RELEASE, __HIP_MEMORY_SCOPE_AGENT);
        __hip_atomic_fetch_add(&c1f[rg * 32], 1u, __ATOMIC_RELEASE, __HIP_MEMORY_SCOPE_AGENT);
    }

    for (int t = 0; t < 32; ++t) {
        const int p = t & 1, q = p ^ 1;

        // wait: h0 v_t and h1 v_t ready (16 arrivals per version)
        if (tid == 0) {
            unsigned tv = 16u * (unsigned)(t + 1);
            while (__hip_atomic_load(&c0f[rg * 32], __ATOMIC_ACQUIRE, __HIP_MEMORY_SCOPE_AGENT) < tv)
                __builtin_amdgcn_s_sleep(2);
            while (__hip_atomic_load(&c1f[rg * 32], __ATOMIC_ACQUIRE, __HIP_MEMORY_SCOPE_AGENT) < tv)
                __builtin_amdgcn_s_sleep(2);
        }
        __syncthreads();

        // -------- phase A: gh0 = h0@w_hh0^T ; gh1 = h1@w_hh1^T --------
        const bf16* h0p = h0g + p * HSZ + (size_t)(R0 + l16) * 256 + quad * 8;
        const bf16* h1p = h1g + p * HSZ + (size_t)(R0 + l16) * 256 + quad * 8;
        fx4 g0[3], g1[3];
#pragma unroll
        for (int g = 0; g < 3; ++g) {
            g0[g] = fx4{0.f, 0.f, 0.f, 0.f};
            g1[g] = fx4{0.f, 0.f, 0.f, 0.f};
        }
#pragma unroll
        for (int kk = 0; kk < 8; ++kk) {
            bf16x8 a = *(const bf16x8*)(h0p + kk * 32);
            bf16x8 c = *(const bf16x8*)(h1p + kk * 32);
            int kb = (kk * 32 + quad * 8) ^ xw;
#pragma unroll
            for (int g = 0; g < 3; ++g) {
                bf16x8 b0 = *(const bf16x8*)&wlds[(0 * 48 + g * 16 + l16) * 256 + kb];
                g0[g] = MFMA16(a, b0, g0[g]);
                bf16x8 b2 = *(const bf16x8*)&wlds[(2 * 48 + g * 16 + l16) * 256 + kb];
                g1[g] = MFMA16(c, b2, g1[g]);
            }
        }
        // layer-0 gates -> h0(t+1) col-slice
#pragma unroll
        for (int r = 0; r < 4; ++r) {
            float rr = sigm(cpv[0][r] + gwv[0][r] + g0[0][r] + bh0[0]);
            float zz = sigm(cpv[1][r] + gwv[1][r] + g0[1][r] + bh0[1]);
            float nn = tanhf(cpv[2][r] + gwv[2][r] + rr * (g0[2][r] + bh0[2]));
            h0m[r] = (1.0f - zz) * nn + zz * h0m[r];
            h0g[q * HSZ + (size_t)(rowc + r) * 256 + colg] = (bf16)h0m[r];
        }
        __syncthreads();   // all h0 stores drained
        if (tid == 0) {
            __threadfence();
            __hip_atomic_fetch_add(&c0f[rg * 32], 1u, __ATOMIC_RELEASE, __HIP_MEMORY_SCOPE_AGENT);
        }

        // prefetch next-step cproj gather (pure inputs; overlaps the wait)
        float cpn[3][4];
        int nid[4];
#pragma unroll
        for (int r = 0; r < 4; ++r)
            nid[r] = tgt[(rowc + r) * 32 + t];   // char id for step t+1
#pragma unroll
        for (int g = 0; g < 3; ++g)
#pragma unroll
            for (int r = 0; r < 4; ++r)
                cpn[g][r] = cproj[(size_t)nid[r] * 768 + g * 256 + colg];

        // wait: h0 v_{t+1} complete across the row-group
        if (tid == 0) {
            unsigned tv = 16u * (unsigned)(t + 2);
            while (__hip_atomic_load(&c0f[rg * 32], __ATOMIC_ACQUIRE, __HIP_MEMORY_SCOPE_AGENT) < tv)
                __builtin_amdgcn_s_sleep(2);
        }
        __syncthreads();

        // -------- phase B: gi1 = h0(t+1)@w_ih1^T --------
        const bf16* h0q = h0g + q * HSZ + (size_t)(R0 + l16) * 256 + quad * 8;
        fx4 gi[3];
#pragma unroll
        for (int g = 0; g < 3; ++g) gi[g] = fx4{0.f, 0.f, 0.f, 0.f};
#pragma unroll
        for (int kk = 0; kk < 8; ++kk) {
            bf16x8 a = *(const bf16x8*)(h0q + kk * 32);
            int kb = (kk * 32 + quad * 8) ^ xw;
#pragma unroll
            for (int g = 0; g < 3; ++g) {
                bf16x8 b = *(const bf16x8*)&wlds[(1 * 48 + g * 16 + l16) * 256 + kb];
                gi[g] = MFMA16(a, b, gi[g]);
            }
        }
        // layer-1 gates (g1 = gh1 from phase A) -> h1(t+1)
#pragma unroll
        for (int r = 0; r < 4; ++r) {
            float rr = sigm(gi[0][r] + bi1[0] + g1[0][r] + bh1[0]);
            float zz = sigm(gi[1][r] + bi1[1] + g1[1][r] + bh1[1]);
            float nn = tanhf(gi[2][r] + bi1[2] + rr * (g1[2][r] + bh1[2]));
            h1m[r] = (1.0f - zz) * nn + zz * h1m[r];
            bf16 hv = (bf16)h1m[r];
            h1g[q * HSZ + (size_t)(rowc + r) * 256 + colg] = hv;
            h1all[((size_t)(rowc + r) * 32 + t) * 256 + colg] = hv;
        }
#pragma unroll
        for (int g = 0; g < 3; ++g)
#pragma unroll
            for (int r = 0; r < 4; ++r) cpv[g][r] = cpn[g][r];

        __syncthreads();   // all h1 stores drained
        if (tid == 0) {
            __threadfence();
            __hip_atomic_fetch_add(&c1f[rg * 32], 1u, __ATOMIC_RELEASE, __HIP_MEMORY_SCOPE_AGENT);
        }
    }
}

// ---------------------------------------------------------------------------
// Final logits: out[m,v] = (h1[m,:] + a2[m>>5,:]) @ pw^T + pb[v],  M=131072.
// ---------------------------------------------------------------------------
__global__ __launch_bounds__(256, 4) void logits_final(
    const bf16*  __restrict__ h1,    // (131072,256) bf16
    const float* __restrict__ a2,    // (4096,256) attn_out (fp32)
    const bf16*  __restrict__ pw,    // (256,256) bf16
    const float* __restrict__ pb,    // (256,)
    float* __restrict__ out)         // (131072,256)
{
    const int tid  = threadIdx.x;
    const int wid  = tid >> 6;
    const int lane = tid & 63;
    const int quad = lane >> 4;
    const int l16  = lane & 15;
    const int m0   = blockIdx.x * 32;
    const int n0   = wid * 64;
    const int b    = m0 >> 5;          // all 32 rows share one batch index

    fx4 acc[4][2];
#pragma unroll
    for (int j = 0; j < 4; ++j) {
        acc[j][0] = fx4{0.f, 0.f, 0.f, 0.f};
        acc[j][1] = fx4{0.f, 0.f, 0.f, 0.f};
    }

    for (int k0 = 0; k0 < 256; k0 += 32) {
        bf16x8 h0 = *(const bf16x8*)(h1 + (size_t)(m0 + l16) * 256 + k0 + quad * 8);
        bf16x8 h1v = *(const bf16x8*)(h1 + (size_t)(m0 + 16 + l16) * 256 + k0 + quad * 8);
        const float* ap = a2 + (size_t)b * 256 + k0 + quad * 8;
        bf16x8 a0 = addcvt8(h0, ap);
        bf16x8 a1 = addcvt8(h1v, ap);
#pragma unroll
        for (int j = 0; j < 4; ++j) {
            bf16x8 bb = *(const bf16x8*)(pw + (size_t)(n0 + j * 16 + l16) * 256 + k0 + quad * 8);
            acc[j][0] = MFMA16(a0, bb, acc[j][0]);
            acc[j][1] = MFMA16(a1, bb, acc[j][1]);
        }
    }

#pragma unroll
    for (int j = 0; j < 4; ++j) {
        int n = n0 + j * 16 + l16;
        float bv = pb[n];
#pragma unroll
        for (int rt = 0; rt < 2; ++rt)
#pragma unroll
            for (int r = 0; r < 4; ++r) {
                int m = m0 + rt * 16 + quad * 4 + r;
                out[(size_t)m * 256 + n] = acc[j][rt][r] + bv;
            }
    }
}

// ---------------------------------------------------------------------------
extern "C" void kernel_launch(void* const* d_in, const int* in_sizes, int n_in,
                              void* d_out, int out_size, void* d_ws, size_t ws_size,
                              hipStream_t stream)
{
    const float* eword      = (const float*)d_in[0];
    const int*   tgt        = (const int*)  d_in[1];
    const float* char_emb   = (const float*)d_in[2];
    const float* ew_w       = (const float*)d_in[3];
    const float* ew_b       = (const float*)d_in[4];
    const float* w_ih0      = (const float*)d_in[5];   // (768, 832)
    const float* w_hh0      = (const float*)d_in[6];
    const float* b_ih0      = (const float*)d_in[7];
    const float* b_hh0      = (const float*)d_in[8];
    const float* w_ih1      = (const float*)d_in[9];
    const float* w_hh1      = (const float*)d_in[10];
    const float* b_ih1      = (const float*)d_in[11];
    const float* b_hh1      = (const float*)d_in[12];
    const float* attn_in_w  = (const float*)d_in[13];  // wq|wk|wv (q,k dead)
    const float* attn_in_b  = (const float*)d_in[14];
    const float* attn_out_w = (const float*)d_in[15];
    const float* attn_out_b = (const float*)d_in[16];
    // d_in[17..18] key_w/key_b dead (len-1 softmax)
    const float* val_w      = (const float*)d_in[19];
    const float* val_b      = (const float*)d_in[20];
    const float* proj_w     = (const float*)d_in[21];
    const float* proj_b     = (const float*)d_in[22];

    char* ws = (char*)d_ws;
    float* h0i   = (float*)ws;  ws += (size_t)4096 * 256 * 4;   //  4 MB
    float* gwrd  = (float*)ws;  ws += (size_t)4096 * 768 * 4;   // 12 MB
    float* cproj = (float*)ws;  ws += (size_t)256  * 768 * 4;   // .75 MB
    float* a2    = (float*)ws;  ws += (size_t)4096 * 256 * 4;   //  4 MB
    // 8 MB region: prologue uses it as buf1/buf2 (fp32); decoder reuses it as
    // the bf16 ping-pong h-state buffers (stream-ordered, no overlap).
    char*  hreg  = ws;          ws += (size_t)8 * 1024 * 1024;
    float* buf1  = (float*)hreg;                       // 4 MB (t1)
    float* buf2  = (float*)(hreg + (size_t)4*1024*1024); // 4 MB (ev)
    bf16*  h0g   = (bf16*)hreg;                        // [2][4096][256] = 4 MB
    bf16*  h1g   = (bf16*)(hreg + (size_t)4*1024*1024);// [2][4096][256] = 4 MB
    bf16*  wbhh0 = (bf16*)ws;   ws += (size_t)768 * 256 * 2;
    bf16*  wbih1 = (bf16*)ws;   ws += (size_t)768 * 256 * 2;
    bf16*  wbhh1 = (bf16*)ws;   ws += (size_t)768 * 256 * 2;
    bf16*  wbprj = (bf16*)ws;   ws += (size_t)256 * 256 * 2;
    bf16*  h1all = (bf16*)ws;   ws += (size_t)4096 * 32 * 256 * 2;  // 67 MB
    unsigned* c0f = (unsigned*)ws; ws += 16 * 32 * 4;  // per-rg h0 counters
    unsigned* c1f = (unsigned*)ws; ws += 16 * 32 * 4;  // per-rg h1 counters

    dim3 blk(256);
    f2b<<<dim3(192), blk, 0, stream>>>(w_hh0, wbhh0, 768 * 256);
    f2b<<<dim3(192), blk, 0, stream>>>(w_ih1, wbih1, 768 * 256);
    f2b<<<dim3(192), blk, 0, stream>>>(w_hh1, wbhh1, 768 * 256);
    f2b<<<dim3(64),  blk, 0, stream>>>(proj_w, wbprj, 256 * 256);
    zero_u32<<<dim3(4), blk, 0, stream>>>(c0f, 2 * 16 * 32);

    // h0 = tanh(eword @ ew_w^T + ew_b)
    gemm_bt<<<dim3(128, 1), blk, 0, stream>>>(eword, 768, ew_w, 768, ew_b, h0i, 256, 1, 768);
    // gword = eword @ w_ih0[:,64:]^T + b_ih0
    gemm_bt<<<dim3(128, 3), blk, 0, stream>>>(eword, 768, w_ih0 + 64, 832, b_ih0, gwrd, 768, 0, 768);
    // cproj = char_emb @ w_ih0[:,:64]^T   (PAD row of char_emb is zero)
    gemm_bt<<<dim3(8, 3),   blk, 0, stream>>>(char_emb, 64, w_ih0, 832, nullptr, cproj, 768, 0, 64);
    // attention chain (static): t1 = ew@vw^T+vb; ev = t1@wv^T+bv; a2 = ev@ao^T+ab
    gemm_bt<<<dim3(128, 1), blk, 0, stream>>>(eword, 768, val_w, 768, val_b, buf1, 256, 0, 768);
    gemm_bt<<<dim3(128, 1), blk, 0, stream>>>(buf1, 256, attn_in_w + 512 * 256, 256, attn_in_b + 512, buf2, 256, 0, 256);
    gemm_bt<<<dim3(128, 1), blk, 0, stream>>>(buf2, 256, attn_out_w, 256, attn_out_b, a2, 256, 0, 256);

    // weight-stationary recurrent decode (cooperative: all 256 blocks resident)
    {
        void* kargs[] = {
            (void*)&tgt, (void*)&h0i, (void*)&gwrd, (void*)&cproj,
            (void*)&wbhh0, (void*)&b_hh0, (void*)&wbih1, (void*)&b_ih1,
            (void*)&wbhh1, (void*)&b_hh1,
            (void*)&h0g, (void*)&h1g, (void*)&c0f, (void*)&c1f, (void*)&h1all
        };
        hipLaunchCooperativeKernel((const void*)decoder_loop, dim3(256), dim3(1024),
                                   kargs, 0, stream);
    }

    // batched logits: out = (h1 + a2) @ pw^T + pb
    logits_final<<<dim3(4096), blk, 0, stream>>>(h1all, a2, wbprj, proj_b, (float*)d_out);
}